// Round 16
// baseline (203.514 us; speedup 1.0000x reference)
//
#include <hip/hip_runtime.h>
#include <math.h>

static constexpr int CH = 512;
static constexpr int GROUPS = 32;
static constexpr int HC = 64;
static constexpr float EPS = 1e-5f;
static constexpr int TI = 4096;
static constexpr int TS = 1024;

typedef __bf16 bf16x8 __attribute__((ext_vector_type(8)));
typedef __bf16 bf16x4 __attribute__((ext_vector_type(4)));
typedef float f32x4 __attribute__((ext_vector_type(4)));

// ---------------------------------------------------------------------------
// GroupNorm partial sums: 1024 blocks = {image: 512, st: 512} x (b, g, chunk).
// ---------------------------------------------------------------------------
__global__ __launch_bounds__(256) void k_gn_partial(const float* __restrict__ img,
                                                    const float* __restrict__ st,
                                                    double* __restrict__ part) {
  int bi = blockIdx.x;
  int which = bi >> 9;       // 0 = image, 1 = st
  int rem = bi & 511;
  int b = rem >> 8;
  int g = (rem >> 3) & 31;
  int chunk = rem & 7;
  const float* X = which ? st : img;
  int T = which ? TS : TI;
  int rows = T >> 3;
  int tid = threadIdx.x;
  const float* base = X + ((size_t)b * T + (size_t)chunk * rows) * CH + g * 16;
  double s1 = 0.0, s2 = 0.0;
  for (int t = tid; t < rows; t += 256) {
    const float4* p = (const float4*)(base + (size_t)t * CH);
#pragma unroll
    for (int q = 0; q < 4; ++q) {
      float4 v = p[q];
      s1 += (double)v.x + (double)v.y + (double)v.z + (double)v.w;
      s2 += (double)v.x * v.x + (double)v.y * v.y + (double)v.z * v.z + (double)v.w * v.w;
    }
  }
  __shared__ double r1[256];
  __shared__ double r2[256];
  r1[tid] = s1;
  r2[tid] = s2;
  __syncthreads();
  for (int s = 128; s > 0; s >>= 1) {
    if (tid < s) { r1[tid] += r1[tid + s]; r2[tid] += r2[tid + s]; }
    __syncthreads();
  }
  if (tid == 0) {
    part[bi * 2 + 0] = r1[0];
    part[bi * 2 + 1] = r2[0];
  }
}

// ---------------------------------------------------------------------------
// GroupNorm finalize: 128 threads, one per (which, b, g). Sums 8 partials.
// ---------------------------------------------------------------------------
__global__ __launch_bounds__(128) void k_gn_final(const double* __restrict__ part,
                                                  float* __restrict__ stats_x,
                                                  float* __restrict__ stats_j) {
  int tid = threadIdx.x;
  int which = tid >> 6;
  int idx = tid & 63;  // b*32 + g
  const double* p = part + ((which << 9) + ((idx >> 5) << 8) + ((idx & 31) << 3)) * 2;
  double s1 = 0.0, s2 = 0.0;
#pragma unroll
  for (int c = 0; c < 8; ++c) {
    s1 += p[c * 2 + 0];
    s2 += p[c * 2 + 1];
  }
  int T = which ? TS : TI;
  double N = 16.0 * T;
  double mu = s1 / N;
  double var = s2 / N - mu * mu;
  float rs = (float)(1.0 / sqrt(var + (double)EPS));
  float* stats = which ? stats_j : stats_x;
  stats[idx * 2 + 0] = (float)mu;
  stats[idx * 2 + 1] = rs;
}

// ---------------------------------------------------------------------------
// GroupNorm apply + bf16 cast for BOTH inputs (merged), writing PACKED
// A-fragment layout: Xp[b][t/16][c/32][lane][8].
// ---------------------------------------------------------------------------
__global__ __launch_bounds__(256) void k_gn_apply2(const float* __restrict__ img,
                                                   const float* __restrict__ st,
                                                   const float* __restrict__ stats_x,
                                                   const float* __restrict__ stats_j,
                                                   const float* __restrict__ xn_w,
                                                   const float* __restrict__ xn_b,
                                                   const float* __restrict__ jn_w,
                                                   const float* __restrict__ jn_b,
                                                   __bf16* __restrict__ Xnp,
                                                   __bf16* __restrict__ stnp) {
  int bi = blockIdx.x;
  bool isimg = bi < 2048;
  const float* X = isimg ? img : st;
  const float* stats = isimg ? stats_x : stats_j;
  const float* nw = isimg ? xn_w : jn_w;
  const float* nb = isimg ? xn_b : jn_b;
  __bf16* Xp = isimg ? Xnp : stnp;
  int T = isimg ? TI : TS;
  size_t idx = ((size_t)(isimg ? bi : bi - 2048) * 256 + threadIdx.x) * 8;

  int b = (int)(idx / ((size_t)T * 512));
  size_t rem = idx - (size_t)b * T * 512;
  int t = (int)(rem >> 9);
  int c = (int)(rem & 511);
  int g = c >> 4;
  float mu = stats[(b * GROUPS + g) * 2 + 0];
  float rs = stats[(b * GROUPS + g) * 2 + 1];
  float4 v0 = *(const float4*)(X + idx);
  float4 v1 = *(const float4*)(X + idx + 4);
  float4 w0 = *(const float4*)(nw + c);
  float4 w1 = *(const float4*)(nw + c + 4);
  float4 q0 = *(const float4*)(nb + c);
  float4 q1 = *(const float4*)(nb + c + 4);
  float xv[8] = {v0.x, v0.y, v0.z, v0.w, v1.x, v1.y, v1.z, v1.w};
  float wv[8] = {w0.x, w0.y, w0.z, w0.w, w1.x, w1.y, w1.z, w1.w};
  float qv[8] = {q0.x, q0.y, q0.z, q0.w, q1.x, q1.y, q1.z, q1.w};
  bf16x8 r;
#pragma unroll
  for (int i = 0; i < 8; ++i) {
    float a = rs * wv[i];
    r[i] = (__bf16)fmaf(xv[i], a, qv[i] - mu * a);
  }
  size_t off = ((((size_t)b * (T >> 4) + (t >> 4)) * 16 + (c >> 5)) * 64 +
                ((c >> 3) & 3) * 16 + (t & 15)) * 8;
  *(bf16x8*)(Xp + off) = r;
}

// ---------------------------------------------------------------------------
// Merged weight pack (all three weight tensors in one launch).
// ---------------------------------------------------------------------------
__global__ __launch_bounds__(256) void k_pack_all(const float* __restrict__ xqkv_w,
                                                  const float* __restrict__ jqkv_w,
                                                  const float* __restrict__ proj_w,
                                                  __bf16* __restrict__ wqb,
                                                  __bf16* __restrict__ wkvb,
                                                  __bf16* __restrict__ wb3) {
  int bi = blockIdx.x;
  if (bi < 384) {
    const float* W = (bi < 128) ? xqkv_w : (jqkv_w + (size_t)CH * CH);
    __bf16* Wp = (bi < 128) ? wqb : wkvb;
    int idx = ((bi < 128) ? bi : bi - 128) * 256 + threadIdx.x;
    int lane = idx & 63;
    int l = lane & 15, g = lane >> 4;
    int cb = (idx >> 6) & 15;
    int ob = idx >> 10;
    const float* src = W + (size_t)(ob * 16 + l) * 512 + cb * 32 + g * 8;
    float4 v0 = *(const float4*)src;
    float4 v1 = *(const float4*)(src + 4);
    float xv[8] = {v0.x, v0.y, v0.z, v0.w, v1.x, v1.y, v1.z, v1.w};
    bf16x8 r;
#pragma unroll
    for (int i = 0; i < 8; ++i) r[i] = (__bf16)xv[i];
    *(bf16x8*)(Wp + (size_t)idx * 8) = r;
  } else {
    int idx = (bi - 384) * 256 + threadIdx.x;
    int lane = idx & 63;
    int l = lane & 15, g = lane >> 4;
    int ob = (idx >> 6) & 31;
    int q = idx >> 11;
    int tap = q % 3;
    int cb = q / 3;
    int o = ob * 16 + l;
    int c = cb * 32 + g * 8;
    bf16x8 r;
#pragma unroll
    for (int j = 0; j < 8; ++j) r[j] = (__bf16)proj_w[((size_t)o * 512 + c + j) * 3 + tap];
    *(bf16x8*)(wb3 + (size_t)idx * 8) = r;
  }
}

// ---------------------------------------------------------------------------
// MFMA 1x1-conv GEMM on packed operands; vectorized transpose epilogues.
// (unchanged from r11 — measured good)
// ---------------------------------------------------------------------------
__global__ __launch_bounds__(256) void k_qkv_mfma(const __bf16* __restrict__ Xp,
                                                  const __bf16* __restrict__ Wp,
                                                  const float* __restrict__ bias,
                                                  __bf16* __restrict__ outQK,
                                                  __bf16* __restrict__ outVp,
                                                  int T) {
  int b = blockIdx.z;
  int o0 = blockIdx.y * 64;
  int tid = threadIdx.x;
  int w = tid >> 6;
  int lane = tid & 63;
  int l = lane & 15;
  int g = lane >> 4;
  int t0 = blockIdx.x * 128 + w * 32;
  int Tb = T >> 4;
  bool vmode = (outVp != nullptr) && (o0 >= 512);

  __shared__ __align__(16) __bf16 Elds[4][2048];  // 4KB per wave

  f32x4 acc[2][4] = {};
  const __bf16* Xb = Xp + (size_t)b * T * 512;

  auto load_c = [&](int cb, bf16x8 (&af)[2], bf16x8 (&wf)[4]) {
#pragma unroll
    for (int m = 0; m < 2; ++m)
      af[m] = *(const bf16x8*)(Xb + ((((size_t)(t0 >> 4) + m) * 16 + cb) * 64 + lane) * 8);
#pragma unroll
    for (int n = 0; n < 4; ++n)
      wf[n] = *(const bf16x8*)(Wp + ((((size_t)(o0 >> 4) + n) * 16 + cb) * 64 + lane) * 8);
  };

  bf16x8 afA[2], wfA[4], afB[2], wfB[4];
#define QKV_LOOP(MMEXPR)                                                        \
  {                                                                             \
    load_c(0, afA, wfA);                                                        \
    _Pragma("unroll") for (int cb = 0; cb < 16; cb += 2) {                      \
      load_c(cb + 1, afB, wfB);                                                 \
      _Pragma("unroll") for (int m = 0; m < 2; ++m)                             \
          _Pragma("unroll") for (int n = 0; n < 4; ++n) {                       \
        bf16x8 af = afA[m], wf = wfA[n];                                        \
        acc[m][n] = MMEXPR;                                                     \
      }                                                                         \
      if (cb + 2 < 16) load_c(cb + 2, afA, wfA);                                \
      _Pragma("unroll") for (int m = 0; m < 2; ++m)                             \
          _Pragma("unroll") for (int n = 0; n < 4; ++n) {                       \
        bf16x8 af = afB[m], wf = wfB[n];                                        \
        acc[m][n] = MMEXPR;                                                     \
      }                                                                         \
    }                                                                           \
  }

  if (!vmode) {
    // swapped: D rows = o (16n+4g+r), cols = t (16m+l)
    QKV_LOOP(__builtin_amdgcn_mfma_f32_16x16x32_bf16(wf, af, acc[m][n], 0, 0, 0))
    float sc = (outVp == nullptr) ? 0.125f * 1.44269504088896f : 1.0f;
    int swz = (l & 7) << 1;
    __bf16(*Eq)[64] = reinterpret_cast<__bf16(*)[64]>(&Elds[w][0]);  // [32][64]
#pragma unroll
    for (int m = 0; m < 2; ++m)
#pragma unroll
      for (int n = 0; n < 4; ++n) {
        f32x4 bv = *(const f32x4*)(bias + o0 + 16 * n + 4 * g);
        bf16x4 pv;
#pragma unroll
        for (int r = 0; r < 4; ++r) pv[r] = (__bf16)((acc[m][n][r] + bv[r]) * sc);
        *(bf16x4*)&Eq[m * 16 + l][((4 * n + g) ^ swz) * 4] = pv;
      }
#pragma unroll
    for (int m = 0; m < 2; ++m)
#pragma unroll
      for (int cbi = 0; cbi < 2; ++cbi) {
        bf16x8 v = *(const bf16x8*)&Eq[m * 16 + l][((8 * cbi + 2 * g) ^ swz) * 4];
        *(bf16x8*)(outQK +
                   ((((size_t)b * Tb + (t0 >> 4) + m) * 16 + (o0 >> 5) + cbi) * 64 + lane) * 8) = v;
      }
  } else {
    // unswapped: D rows = s (16m+4g+r), cols = c (16n+l)
    QKV_LOOP(__builtin_amdgcn_mfma_f32_16x16x32_bf16(af, wf, acc[m][n], 0, 0, 0))
    int swzv = l & 6;
    __bf16(*Ev)[32] = reinterpret_cast<__bf16(*)[32]>(&Elds[w][0]);  // [64 c][32 s]
#pragma unroll
    for (int m = 0; m < 2; ++m)
#pragma unroll
      for (int n = 0; n < 4; ++n) {
        float bo = bias[o0 + 16 * n + l];
        bf16x4 pv;
#pragma unroll
        for (int r = 0; r < 4; ++r) pv[r] = (__bf16)(acc[m][n][r] + bo);
        *(bf16x4*)&Ev[16 * n + l][((4 * m + g) ^ swzv) * 4] = pv;
      }
#pragma unroll
    for (int n = 0; n < 4; ++n) {
      bf16x8 v = *(const bf16x8*)&Ev[16 * n + l][((2 * g) ^ swzv) * 4];
      int cb16 = ((o0 - 512) >> 4) + n;
      *(bf16x8*)(outVp + ((((size_t)b * 32 + cb16) * 32 + (t0 >> 5)) * 64 + lane) * 8) = v;
    }
  }
#undef QKV_LOOP
}

// ---------------------------------------------------------------------------
// MFMA flash cross-attention, swapped-QK form, s-split across 2 waves.
// r13 structure (best measured) with the s-loop FULLY UNROLLED: all global
// K/V fragment loads become hoistable by the scheduler (compiler-driven
// prefetch within the 128-VGPR cap); P-LDS reuse correctly serializes the
// exp->PV chain per tile. Qp pre-scaled by 0.125*log2e -> exp2f.
// ---------------------------------------------------------------------------
__global__ __launch_bounds__(128, 4) void k_attn_mfma(const __bf16* __restrict__ Qp,
                                                      const __bf16* __restrict__ Kp,
                                                      const __bf16* __restrict__ Vp,
                                                      __bf16* __restrict__ outA) {
  int b = blockIdx.z;
  int h = blockIdx.y;
  int tid = threadIdx.x;
  int w = tid >> 6;  // s-half
  int lane = tid & 63;
  int l = lane & 15;
  int g = lane >> 4;
  int t0 = blockIdx.x * 32;
  int swz = (l & 7) << 1;

  __shared__ __align__(16) __bf16 Pt[2][2][16][64];  // [wave][tb][t-row l][s], 8KB
  __shared__ float Lred[64][2];
  // Ored aliases the whole Pt region (dead after both waves' s-loops).
  float* Ored = (float*)&Pt[0][0][0][0];  // 64 lanes x 32 floats = 8KB

  // Q fragments (packed, contiguous per wave)
  bf16x8 qf[2][2];
#pragma unroll
  for (int m = 0; m < 2; ++m)
#pragma unroll
    for (int ks = 0; ks < 2; ++ks)
      qf[m][ks] = *(const bf16x8*)(Qp + ((((size_t)b * 256 + (t0 >> 4) + m) * 16 +
                                          2 * h + ks) * 64 + lane) * 8);

  f32x4 o_acc[2][4] = {};  // [tb][n]: c = 16n+4g+r, t = 16tb+l
  float rs_acc[2] = {};

  int s_base = w * 512;
#pragma unroll
  for (int si = 0; si < 8; ++si) {
    int s0 = s_base + si * 64;
    // K fragments (packed)
    bf16x8 kf[4][2];
#pragma unroll
    for (int n = 0; n < 4; ++n)
#pragma unroll
      for (int ks = 0; ks < 2; ++ks)
        kf[n][ks] = *(const bf16x8*)(Kp + ((((size_t)b * 64 + (s0 >> 4) + n) * 16 +
                                            2 * h + ks) * 64 + lane) * 8);
    // V fragments (packed)
    bf16x8 vf[4][2];
#pragma unroll
    for (int n = 0; n < 4; ++n)
#pragma unroll
      for (int ks = 0; ks < 2; ++ks)
        vf[n][ks] = *(const bf16x8*)(Vp + ((((size_t)b * 32 + h * 4 + n) * 32 +
                                            (s0 >> 5) + ks) * 64 + lane) * 8);
    // S^T = K Q^T : sT[sb][tb], row s = 16sb+4g+r, col t = 16tb+l
    f32x4 sT[4][2];
#pragma unroll
    for (int sb = 0; sb < 4; ++sb)
#pragma unroll
      for (int tb = 0; tb < 2; ++tb) {
        f32x4 z = {0.f, 0.f, 0.f, 0.f};
        z = __builtin_amdgcn_mfma_f32_16x16x32_bf16(kf[sb][0], qf[tb][0], z, 0, 0, 0);
        sT[sb][tb] = __builtin_amdgcn_mfma_f32_16x16x32_bf16(kf[sb][1], qf[tb][1], z, 0, 0, 0);
      }
    // p = exp2(S*log2e); partial t-row sums; vectorized b64 P writes
#pragma unroll
    for (int tb = 0; tb < 2; ++tb)
#pragma unroll
      for (int sb = 0; sb < 4; ++sb) {
        float p0 = exp2f(sT[sb][tb][0]);
        float p1 = exp2f(sT[sb][tb][1]);
        float p2 = exp2f(sT[sb][tb][2]);
        float p3 = exp2f(sT[sb][tb][3]);
        rs_acc[tb] += (p0 + p1) + (p2 + p3);
        bf16x4 pv;
        pv[0] = (__bf16)p0;
        pv[1] = (__bf16)p1;
        pv[2] = (__bf16)p2;
        pv[3] = (__bf16)p3;
        *(bf16x4*)&Pt[w][tb][l][((4 * sb + g) ^ swz) * 4] = pv;
      }
    // P B-fragments: col t = 16tb+l, k = s = 32ks+8g+i
    bf16x8 pa[2][2];
#pragma unroll
    for (int tb = 0; tb < 2; ++tb)
#pragma unroll
      for (int ks = 0; ks < 2; ++ks)
        pa[tb][ks] = *(const bf16x8*)&Pt[w][tb][l][((8 * ks + 2 * g) ^ swz) * 4];
    // O^T += V P : D rows c = 16n+4g+r, cols t = 16tb+l
#pragma unroll
    for (int tb = 0; tb < 2; ++tb)
#pragma unroll
      for (int n = 0; n < 4; ++n) {
        o_acc[tb][n] = __builtin_amdgcn_mfma_f32_16x16x32_bf16(vf[n][0], pa[tb][0], o_acc[tb][n], 0, 0, 0);
        o_acc[tb][n] = __builtin_amdgcn_mfma_f32_16x16x32_bf16(vf[n][1], pa[tb][1], o_acc[tb][n], 0, 0, 0);
      }
  }

  // cross-wave combine (linear in s). Pt is dead for BOTH waves after this
  // barrier, so wave 1's partial O can safely overwrite it.
  __syncthreads();
  if (w == 1) {
#pragma unroll
    for (int tb = 0; tb < 2; ++tb) {
#pragma unroll
      for (int n = 0; n < 4; ++n)
#pragma unroll
        for (int r = 0; r < 4; ++r) Ored[lane * 32 + tb * 16 + n * 4 + r] = o_acc[tb][n][r];
      Lred[lane][tb] = rs_acc[tb];
    }
  }
  __syncthreads();
  if (w == 0) {
#pragma unroll
    for (int tb = 0; tb < 2; ++tb) {
#pragma unroll
      for (int n = 0; n < 4; ++n)
#pragma unroll
        for (int r = 0; r < 4; ++r) o_acc[tb][n][r] += Ored[lane * 32 + tb * 16 + n * 4 + r];
      float v = rs_acc[tb] + Lred[lane][tb];
      v += __shfl_xor(v, 16, 64);
      v += __shfl_xor(v, 32, 64);
      float inv = 1.f / v;
      // normalized b64 stores: t = t0+16tb+l, c = h*64+16n+4g+r (4 consecutive)
#pragma unroll
      for (int n = 0; n < 4; ++n) {
        bf16x4 ov;
#pragma unroll
        for (int r = 0; r < 4; ++r) ov[r] = (__bf16)(o_acc[tb][n][r] * inv);
        *(bf16x4*)(outA + ((size_t)b * TI + t0 + 16 * tb + l) * 512 + h * 64 + 16 * n + 4 * g) = ov;
      }
    }
  }
}

// ---------------------------------------------------------------------------
// MFMA conv3 (k=3, SAME) + bias + transposed residual, out [B, C, T] fp32.
// (unchanged from r11 — measured good)
// ---------------------------------------------------------------------------
__global__ __launch_bounds__(256) void k_conv3_mfma(const __bf16* __restrict__ A,
                                                    const __bf16* __restrict__ W3p,
                                                    const float* __restrict__ bias,
                                                    const float* __restrict__ image,
                                                    float* __restrict__ out) {
  int b = blockIdx.z;
  int o0 = blockIdx.y * 64;
  int ob0 = o0 >> 4;
  int tid = threadIdx.x;
  int w = tid >> 6;
  int lane = tid & 63;
  int l = lane & 15;
  int g = lane >> 4;
  int t0 = blockIdx.x * 128;
  int t0w = t0 + w * 32;

  __shared__ __align__(16) __bf16 Alds[2][130 * 32];
  __shared__ __align__(16) __bf16 Wlds[2][12 * 512];

  const __bf16* Ab = A + (size_t)b * TI * 512;

  auto stage = [&](int cb, int buf) {
#pragma unroll
    for (int pass = 0; pass < 3; ++pass) {
      int gi = tid + pass * 256;
      if (gi < 520) {
        int r = gi >> 2, gg = gi & 3;
        int t = t0 - 1 + r;
        bf16x8 v = {};
        if (t >= 0 && t < TI) v = *(const bf16x8*)(Ab + (size_t)t * 512 + cb * 32 + gg * 8);
        *(bf16x8*)&Alds[buf][r * 32 + ((gg ^ (r & 3)) << 3)] = v;
      }
    }
#pragma unroll
    for (int ch = w; ch < 12; ch += 4) {
      bf16x8 v = *(const bf16x8*)(W3p + ((((size_t)cb * 3 + (ch >> 2)) * 32 + ob0 +
                                          (ch & 3)) * 64 + lane) * 8);
      *(bf16x8*)&Wlds[buf][ch * 512 + lane * 8] = v;
    }
  };

  f32x4 acc[2][4] = {};

  stage(0, 0);
  __syncthreads();
#pragma unroll 1
  for (int cs = 0; cs < 16; ++cs) {
    int cur = cs & 1;
    if (cs < 15) stage(cs + 1, cur ^ 1);
    bf16x8 af[3][2], wf[3][4];
#pragma unroll
    for (int tap = 0; tap < 3; ++tap) {
#pragma unroll
      for (int m = 0; m < 2; ++m) {
        int r = w * 32 + 16 * m + l + tap;
        af[tap][m] = *(const bf16x8*)&Alds[cur][r * 32 + ((g ^ (r & 3)) << 3)];
      }
#pragma unroll
      for (int n = 0; n < 4; ++n)
        wf[tap][n] = *(const bf16x8*)&Wlds[cur][(tap * 4 + n) * 512 + lane * 8];
    }
#pragma unroll
    for (int tap = 0; tap < 3; ++tap)
#pragma unroll
      for (int m = 0; m < 2; ++m)
#pragma unroll
        for (int n = 0; n < 4; ++n)
          acc[m][n] =
              __builtin_amdgcn_mfma_f32_16x16x32_bf16(af[tap][m], wf[tap][n], acc[m][n], 0, 0, 0);
    __syncthreads();
  }

#pragma unroll
  for (int m = 0; m < 2; ++m) {
    int tb = t0w + 16 * m + 4 * g;
#pragma unroll
    for (int n = 0; n < 4; ++n) {
      int o = o0 + 16 * n + l;
      float bo = bias[o];
      f32x4 r;
#pragma unroll
      for (int rr = 0; rr < 4; ++rr)
        r[rr] = acc[m][n][rr] + bo + image[((size_t)b * TI + tb + rr) * CH + o];
      *(f32x4*)(out + ((size_t)b * CH + o) * TI + tb) = r;
    }
  }
}

extern "C" void kernel_launch(void* const* d_in, const int* in_sizes, int n_in,
                              void* d_out, int out_size, void* d_ws, size_t ws_size,
                              hipStream_t stream) {
  const float* image = (const float*)d_in[0];
  const float* st = (const float*)d_in[1];
  const float* xn_w = (const float*)d_in[2];
  const float* xn_b = (const float*)d_in[3];
  const float* jn_w = (const float*)d_in[4];
  const float* jn_b = (const float*)d_in[5];
  const float* xqkv_w = (const float*)d_in[6];
  const float* xqkv_b = (const float*)d_in[7];
  const float* jqkv_w = (const float*)d_in[8];
  const float* jqkv_b = (const float*)d_in[9];
  const float* proj_w = (const float*)d_in[10];
  const float* proj_b = (const float*)d_in[11];
  float* out = (float*)d_out;
  float* ws = (float*)d_ws;

  double* part = (double*)ws;                           // 2048 doubles = 16KB
  float* stats_x = ws + 4096;                           // 128 f32
  float* stats_j = ws + 4096 + 128;                     // 128 f32
  __bf16* Xnp = (__bf16*)(ws + 4096 + 256);             // packed GN'd image (8.4MB)
  __bf16* abuf = Xnp;                                   // alias: row-major attn out
  __bf16* stnp = Xnp + (size_t)2 * TI * CH;             // packed GN'd st (2.1MB)
  __bf16* wqb = stnp + (size_t)2 * TS * CH;             // packed Q weights
  __bf16* wkvb = wqb + (size_t)CH * CH;                 // packed KV weights
  __bf16* wb3 = wkvb + (size_t)2 * CH * CH;             // packed conv3 weights
  __bf16* Qp = wb3 + (size_t)3 * CH * CH;               // packed Q (8.4MB)
  __bf16* Kp = Qp + (size_t)2 * TI * CH;                // packed K (2.1MB)
  __bf16* Vp = Kp + (size_t)2 * TS * CH;                // packed V (2.1MB)

  k_gn_partial<<<dim3(1024), dim3(256), 0, stream>>>(image, st, part);
  k_gn_final<<<dim3(1), dim3(128), 0, stream>>>(part, stats_x, stats_j);

  k_gn_apply2<<<dim3(2560), dim3(256), 0, stream>>>(image, st, stats_x, stats_j,
                                                    xn_w, xn_b, jn_w, jn_b, Xnp, stnp);

  k_pack_all<<<dim3(768), dim3(256), 0, stream>>>(xqkv_w, jqkv_w, proj_w, wqb, wkvb, wb3);

  // image: Q = rows 0..511 of xqkv -> packed Q (pre-scaled by 0.125*log2e)
  k_qkv_mfma<<<dim3(TI / 128, CH / 64, 2), dim3(256), 0, stream>>>(
      Xnp, wqb, xqkv_b, Qp, nullptr, TI);
  // st: K,V = rows 512..1535 of jqkv -> packed K, packed V
  k_qkv_mfma<<<dim3(TS / 128, 1024 / 64, 2), dim3(256), 0, stream>>>(
      stnp, wkvb, jqkv_b + CH, Kp, Vp, TS);

  k_attn_mfma<<<dim3(TI / 32, 8, 2), dim3(128), 0, stream>>>(Qp, Kp, Vp, abuf);

  k_conv3_mfma<<<dim3(TI / 128, CH / 64, 2), dim3(256), 0, stream>>>(
      abuf, wb3, proj_b, image, out);
}

// Round 17
// 165.415 us; speedup vs baseline: 1.2303x; 1.2303x over previous
//
#include <hip/hip_runtime.h>
#include <math.h>

static constexpr int CH = 512;
static constexpr int GROUPS = 32;
static constexpr int HC = 64;
static constexpr float EPS = 1e-5f;
static constexpr int TI = 4096;
static constexpr int TS = 1024;

typedef __bf16 bf16x8 __attribute__((ext_vector_type(8)));
typedef __bf16 bf16x4 __attribute__((ext_vector_type(4)));
typedef float f32x4 __attribute__((ext_vector_type(4)));

// ---------------------------------------------------------------------------
// GroupNorm partial sums: 1024 blocks = {image: 512, st: 512} x (b, g, chunk).
// ---------------------------------------------------------------------------
__global__ __launch_bounds__(256) void k_gn_partial(const float* __restrict__ img,
                                                    const float* __restrict__ st,
                                                    double* __restrict__ part) {
  int bi = blockIdx.x;
  int which = bi >> 9;       // 0 = image, 1 = st
  int rem = bi & 511;
  int b = rem >> 8;
  int g = (rem >> 3) & 31;
  int chunk = rem & 7;
  const float* X = which ? st : img;
  int T = which ? TS : TI;
  int rows = T >> 3;
  int tid = threadIdx.x;
  const float* base = X + ((size_t)b * T + (size_t)chunk * rows) * CH + g * 16;
  double s1 = 0.0, s2 = 0.0;
  for (int t = tid; t < rows; t += 256) {
    const float4* p = (const float4*)(base + (size_t)t * CH);
#pragma unroll
    for (int q = 0; q < 4; ++q) {
      float4 v = p[q];
      s1 += (double)v.x + (double)v.y + (double)v.z + (double)v.w;
      s2 += (double)v.x * v.x + (double)v.y * v.y + (double)v.z * v.z + (double)v.w * v.w;
    }
  }
  __shared__ double r1[256];
  __shared__ double r2[256];
  r1[tid] = s1;
  r2[tid] = s2;
  __syncthreads();
  for (int s = 128; s > 0; s >>= 1) {
    if (tid < s) { r1[tid] += r1[tid + s]; r2[tid] += r2[tid + s]; }
    __syncthreads();
  }
  if (tid == 0) {
    part[bi * 2 + 0] = r1[0];
    part[bi * 2 + 1] = r2[0];
  }
}

// ---------------------------------------------------------------------------
// GroupNorm finalize: 128 threads, one per (which, b, g). Sums 8 partials.
// ---------------------------------------------------------------------------
__global__ __launch_bounds__(128) void k_gn_final(const double* __restrict__ part,
                                                  float* __restrict__ stats_x,
                                                  float* __restrict__ stats_j) {
  int tid = threadIdx.x;
  int which = tid >> 6;
  int idx = tid & 63;  // b*32 + g
  const double* p = part + ((which << 9) + ((idx >> 5) << 8) + ((idx & 31) << 3)) * 2;
  double s1 = 0.0, s2 = 0.0;
#pragma unroll
  for (int c = 0; c < 8; ++c) {
    s1 += p[c * 2 + 0];
    s2 += p[c * 2 + 1];
  }
  int T = which ? TS : TI;
  double N = 16.0 * T;
  double mu = s1 / N;
  double var = s2 / N - mu * mu;
  float rs = (float)(1.0 / sqrt(var + (double)EPS));
  float* stats = which ? stats_j : stats_x;
  stats[idx * 2 + 0] = (float)mu;
  stats[idx * 2 + 1] = rs;
}

// ---------------------------------------------------------------------------
// GroupNorm apply + bf16 cast for BOTH inputs (merged), writing PACKED
// A-fragment layout: Xp[b][t/16][c/32][lane][8].
// ---------------------------------------------------------------------------
__global__ __launch_bounds__(256) void k_gn_apply2(const float* __restrict__ img,
                                                   const float* __restrict__ st,
                                                   const float* __restrict__ stats_x,
                                                   const float* __restrict__ stats_j,
                                                   const float* __restrict__ xn_w,
                                                   const float* __restrict__ xn_b,
                                                   const float* __restrict__ jn_w,
                                                   const float* __restrict__ jn_b,
                                                   __bf16* __restrict__ Xnp,
                                                   __bf16* __restrict__ stnp) {
  int bi = blockIdx.x;
  bool isimg = bi < 2048;
  const float* X = isimg ? img : st;
  const float* stats = isimg ? stats_x : stats_j;
  const float* nw = isimg ? xn_w : jn_w;
  const float* nb = isimg ? xn_b : jn_b;
  __bf16* Xp = isimg ? Xnp : stnp;
  int T = isimg ? TI : TS;
  size_t idx = ((size_t)(isimg ? bi : bi - 2048) * 256 + threadIdx.x) * 8;

  int b = (int)(idx / ((size_t)T * 512));
  size_t rem = idx - (size_t)b * T * 512;
  int t = (int)(rem >> 9);
  int c = (int)(rem & 511);
  int g = c >> 4;
  float mu = stats[(b * GROUPS + g) * 2 + 0];
  float rs = stats[(b * GROUPS + g) * 2 + 1];
  float4 v0 = *(const float4*)(X + idx);
  float4 v1 = *(const float4*)(X + idx + 4);
  float4 w0 = *(const float4*)(nw + c);
  float4 w1 = *(const float4*)(nw + c + 4);
  float4 q0 = *(const float4*)(nb + c);
  float4 q1 = *(const float4*)(nb + c + 4);
  float xv[8] = {v0.x, v0.y, v0.z, v0.w, v1.x, v1.y, v1.z, v1.w};
  float wv[8] = {w0.x, w0.y, w0.z, w0.w, w1.x, w1.y, w1.z, w1.w};
  float qv[8] = {q0.x, q0.y, q0.z, q0.w, q1.x, q1.y, q1.z, q1.w};
  bf16x8 r;
#pragma unroll
  for (int i = 0; i < 8; ++i) {
    float a = rs * wv[i];
    r[i] = (__bf16)fmaf(xv[i], a, qv[i] - mu * a);
  }
  size_t off = ((((size_t)b * (T >> 4) + (t >> 4)) * 16 + (c >> 5)) * 64 +
                ((c >> 3) & 3) * 16 + (t & 15)) * 8;
  *(bf16x8*)(Xp + off) = r;
}

// ---------------------------------------------------------------------------
// Merged weight pack (all three weight tensors in one launch).
// ---------------------------------------------------------------------------
__global__ __launch_bounds__(256) void k_pack_all(const float* __restrict__ xqkv_w,
                                                  const float* __restrict__ jqkv_w,
                                                  const float* __restrict__ proj_w,
                                                  __bf16* __restrict__ wqb,
                                                  __bf16* __restrict__ wkvb,
                                                  __bf16* __restrict__ wb3) {
  int bi = blockIdx.x;
  if (bi < 384) {
    const float* W = (bi < 128) ? xqkv_w : (jqkv_w + (size_t)CH * CH);
    __bf16* Wp = (bi < 128) ? wqb : wkvb;
    int idx = ((bi < 128) ? bi : bi - 128) * 256 + threadIdx.x;
    int lane = idx & 63;
    int l = lane & 15, g = lane >> 4;
    int cb = (idx >> 6) & 15;
    int ob = idx >> 10;
    const float* src = W + (size_t)(ob * 16 + l) * 512 + cb * 32 + g * 8;
    float4 v0 = *(const float4*)src;
    float4 v1 = *(const float4*)(src + 4);
    float xv[8] = {v0.x, v0.y, v0.z, v0.w, v1.x, v1.y, v1.z, v1.w};
    bf16x8 r;
#pragma unroll
    for (int i = 0; i < 8; ++i) r[i] = (__bf16)xv[i];
    *(bf16x8*)(Wp + (size_t)idx * 8) = r;
  } else {
    int idx = (bi - 384) * 256 + threadIdx.x;
    int lane = idx & 63;
    int l = lane & 15, g = lane >> 4;
    int ob = (idx >> 6) & 31;
    int q = idx >> 11;
    int tap = q % 3;
    int cb = q / 3;
    int o = ob * 16 + l;
    int c = cb * 32 + g * 8;
    bf16x8 r;
#pragma unroll
    for (int j = 0; j < 8; ++j) r[j] = (__bf16)proj_w[((size_t)o * 512 + c + j) * 3 + tap];
    *(bf16x8*)(wb3 + (size_t)idx * 8) = r;
  }
}

// ---------------------------------------------------------------------------
// MFMA 1x1-conv GEMM on packed operands; vectorized transpose epilogues.
// (unchanged from r11 — measured good)
// ---------------------------------------------------------------------------
__global__ __launch_bounds__(256) void k_qkv_mfma(const __bf16* __restrict__ Xp,
                                                  const __bf16* __restrict__ Wp,
                                                  const float* __restrict__ bias,
                                                  __bf16* __restrict__ outQK,
                                                  __bf16* __restrict__ outVp,
                                                  int T) {
  int b = blockIdx.z;
  int o0 = blockIdx.y * 64;
  int tid = threadIdx.x;
  int w = tid >> 6;
  int lane = tid & 63;
  int l = lane & 15;
  int g = lane >> 4;
  int t0 = blockIdx.x * 128 + w * 32;
  int Tb = T >> 4;
  bool vmode = (outVp != nullptr) && (o0 >= 512);

  __shared__ __align__(16) __bf16 Elds[4][2048];  // 4KB per wave

  f32x4 acc[2][4] = {};
  const __bf16* Xb = Xp + (size_t)b * T * 512;

  auto load_c = [&](int cb, bf16x8 (&af)[2], bf16x8 (&wf)[4]) {
#pragma unroll
    for (int m = 0; m < 2; ++m)
      af[m] = *(const bf16x8*)(Xb + ((((size_t)(t0 >> 4) + m) * 16 + cb) * 64 + lane) * 8);
#pragma unroll
    for (int n = 0; n < 4; ++n)
      wf[n] = *(const bf16x8*)(Wp + ((((size_t)(o0 >> 4) + n) * 16 + cb) * 64 + lane) * 8);
  };

  bf16x8 afA[2], wfA[4], afB[2], wfB[4];
#define QKV_LOOP(MMEXPR)                                                        \
  {                                                                             \
    load_c(0, afA, wfA);                                                        \
    _Pragma("unroll") for (int cb = 0; cb < 16; cb += 2) {                      \
      load_c(cb + 1, afB, wfB);                                                 \
      _Pragma("unroll") for (int m = 0; m < 2; ++m)                             \
          _Pragma("unroll") for (int n = 0; n < 4; ++n) {                       \
        bf16x8 af = afA[m], wf = wfA[n];                                        \
        acc[m][n] = MMEXPR;                                                     \
      }                                                                         \
      if (cb + 2 < 16) load_c(cb + 2, afA, wfA);                                \
      _Pragma("unroll") for (int m = 0; m < 2; ++m)                             \
          _Pragma("unroll") for (int n = 0; n < 4; ++n) {                       \
        bf16x8 af = afB[m], wf = wfB[n];                                        \
        acc[m][n] = MMEXPR;                                                     \
      }                                                                         \
    }                                                                           \
  }

  if (!vmode) {
    // swapped: D rows = o (16n+4g+r), cols = t (16m+l)
    QKV_LOOP(__builtin_amdgcn_mfma_f32_16x16x32_bf16(wf, af, acc[m][n], 0, 0, 0))
    float sc = (outVp == nullptr) ? 0.125f * 1.44269504088896f : 1.0f;
    int swz = (l & 7) << 1;
    __bf16(*Eq)[64] = reinterpret_cast<__bf16(*)[64]>(&Elds[w][0]);  // [32][64]
#pragma unroll
    for (int m = 0; m < 2; ++m)
#pragma unroll
      for (int n = 0; n < 4; ++n) {
        f32x4 bv = *(const f32x4*)(bias + o0 + 16 * n + 4 * g);
        bf16x4 pv;
#pragma unroll
        for (int r = 0; r < 4; ++r) pv[r] = (__bf16)((acc[m][n][r] + bv[r]) * sc);
        *(bf16x4*)&Eq[m * 16 + l][((4 * n + g) ^ swz) * 4] = pv;
      }
#pragma unroll
    for (int m = 0; m < 2; ++m)
#pragma unroll
      for (int cbi = 0; cbi < 2; ++cbi) {
        bf16x8 v = *(const bf16x8*)&Eq[m * 16 + l][((8 * cbi + 2 * g) ^ swz) * 4];
        *(bf16x8*)(outQK +
                   ((((size_t)b * Tb + (t0 >> 4) + m) * 16 + (o0 >> 5) + cbi) * 64 + lane) * 8) = v;
      }
  } else {
    // unswapped: D rows = s (16m+4g+r), cols = c (16n+l)
    QKV_LOOP(__builtin_amdgcn_mfma_f32_16x16x32_bf16(af, wf, acc[m][n], 0, 0, 0))
    int swzv = l & 6;
    __bf16(*Ev)[32] = reinterpret_cast<__bf16(*)[32]>(&Elds[w][0]);  // [64 c][32 s]
#pragma unroll
    for (int m = 0; m < 2; ++m)
#pragma unroll
      for (int n = 0; n < 4; ++n) {
        float bo = bias[o0 + 16 * n + l];
        bf16x4 pv;
#pragma unroll
        for (int r = 0; r < 4; ++r) pv[r] = (__bf16)(acc[m][n][r] + bo);
        *(bf16x4*)&Ev[16 * n + l][((4 * m + g) ^ swzv) * 4] = pv;
      }
#pragma unroll
    for (int n = 0; n < 4; ++n) {
      bf16x8 v = *(const bf16x8*)&Ev[16 * n + l][((2 * g) ^ swzv) * 4];
      int cb16 = ((o0 - 512) >> 4) + n;
      *(bf16x8*)(outVp + ((((size_t)b * 32 + cb16) * 32 + (t0 >> 5)) * 64 + lane) * 8) = v;
    }
  }
#undef QKV_LOOP
}

// ---------------------------------------------------------------------------
// MFMA flash cross-attention, swapped-QK form, s-split across 2 waves.
// Exact r13 instruction stream (best measured: 45.6us, VGPR 64, no spill)
// + s_setprio(1)/(0) around the MFMA clusters (T5; zero register cost).
// Qp pre-scaled by 0.125*log2e -> exp2f.
// ---------------------------------------------------------------------------
__global__ __launch_bounds__(128, 4) void k_attn_mfma(const __bf16* __restrict__ Qp,
                                                      const __bf16* __restrict__ Kp,
                                                      const __bf16* __restrict__ Vp,
                                                      __bf16* __restrict__ outA) {
  int b = blockIdx.z;
  int h = blockIdx.y;
  int tid = threadIdx.x;
  int w = tid >> 6;  // s-half
  int lane = tid & 63;
  int l = lane & 15;
  int g = lane >> 4;
  int t0 = blockIdx.x * 32;
  int swz = (l & 7) << 1;

  __shared__ __align__(16) __bf16 Pt[2][2][16][64];  // [wave][tb][t-row l][s], 8KB
  __shared__ float Lred[64][2];
  // Ored aliases the whole Pt region (dead after both waves' s-loops).
  float* Ored = (float*)&Pt[0][0][0][0];  // 64 lanes x 32 floats = 8KB

  // Q fragments (packed, contiguous per wave)
  bf16x8 qf[2][2];
#pragma unroll
  for (int m = 0; m < 2; ++m)
#pragma unroll
    for (int ks = 0; ks < 2; ++ks)
      qf[m][ks] = *(const bf16x8*)(Qp + ((((size_t)b * 256 + (t0 >> 4) + m) * 16 +
                                          2 * h + ks) * 64 + lane) * 8);

  f32x4 o_acc[2][4] = {};  // [tb][n]: c = 16n+4g+r, t = 16tb+l
  float rs_acc[2] = {};

  int s_base = w * 512;
#pragma unroll 1
  for (int s0 = s_base; s0 < s_base + 512; s0 += 64) {
    // K fragments (packed)
    bf16x8 kf[4][2];
#pragma unroll
    for (int n = 0; n < 4; ++n)
#pragma unroll
      for (int ks = 0; ks < 2; ++ks)
        kf[n][ks] = *(const bf16x8*)(Kp + ((((size_t)b * 64 + (s0 >> 4) + n) * 16 +
                                            2 * h + ks) * 64 + lane) * 8);
    // V fragments (packed)
    bf16x8 vf[4][2];
#pragma unroll
    for (int n = 0; n < 4; ++n)
#pragma unroll
      for (int ks = 0; ks < 2; ++ks)
        vf[n][ks] = *(const bf16x8*)(Vp + ((((size_t)b * 32 + h * 4 + n) * 32 +
                                            (s0 >> 5) + ks) * 64 + lane) * 8);
    // S^T = K Q^T : sT[sb][tb], row s = 16sb+4g+r, col t = 16tb+l
    f32x4 sT[4][2];
    __builtin_amdgcn_s_setprio(1);
#pragma unroll
    for (int sb = 0; sb < 4; ++sb)
#pragma unroll
      for (int tb = 0; tb < 2; ++tb) {
        f32x4 z = {0.f, 0.f, 0.f, 0.f};
        z = __builtin_amdgcn_mfma_f32_16x16x32_bf16(kf[sb][0], qf[tb][0], z, 0, 0, 0);
        sT[sb][tb] = __builtin_amdgcn_mfma_f32_16x16x32_bf16(kf[sb][1], qf[tb][1], z, 0, 0, 0);
      }
    __builtin_amdgcn_s_setprio(0);
    // p = exp2(S*log2e); partial t-row sums; vectorized b64 P writes
#pragma unroll
    for (int tb = 0; tb < 2; ++tb)
#pragma unroll
      for (int sb = 0; sb < 4; ++sb) {
        float p0 = exp2f(sT[sb][tb][0]);
        float p1 = exp2f(sT[sb][tb][1]);
        float p2 = exp2f(sT[sb][tb][2]);
        float p3 = exp2f(sT[sb][tb][3]);
        rs_acc[tb] += (p0 + p1) + (p2 + p3);
        bf16x4 pv;
        pv[0] = (__bf16)p0;
        pv[1] = (__bf16)p1;
        pv[2] = (__bf16)p2;
        pv[3] = (__bf16)p3;
        *(bf16x4*)&Pt[w][tb][l][((4 * sb + g) ^ swz) * 4] = pv;
      }
    // P B-fragments: col t = 16tb+l, k = s = 32ks+8g+i
    bf16x8 pa[2][2];
#pragma unroll
    for (int tb = 0; tb < 2; ++tb)
#pragma unroll
      for (int ks = 0; ks < 2; ++ks)
        pa[tb][ks] = *(const bf16x8*)&Pt[w][tb][l][((8 * ks + 2 * g) ^ swz) * 4];
    // O^T += V P : D rows c = 16n+4g+r, cols t = 16tb+l
    __builtin_amdgcn_s_setprio(1);
#pragma unroll
    for (int tb = 0; tb < 2; ++tb)
#pragma unroll
      for (int n = 0; n < 4; ++n) {
        o_acc[tb][n] = __builtin_amdgcn_mfma_f32_16x16x32_bf16(vf[n][0], pa[tb][0], o_acc[tb][n], 0, 0, 0);
        o_acc[tb][n] = __builtin_amdgcn_mfma_f32_16x16x32_bf16(vf[n][1], pa[tb][1], o_acc[tb][n], 0, 0, 0);
      }
    __builtin_amdgcn_s_setprio(0);
  }

  // cross-wave combine (linear in s). Pt is dead for BOTH waves after this
  // barrier, so wave 1's partial O can safely overwrite it.
  __syncthreads();
  if (w == 1) {
#pragma unroll
    for (int tb = 0; tb < 2; ++tb) {
#pragma unroll
      for (int n = 0; n < 4; ++n)
#pragma unroll
        for (int r = 0; r < 4; ++r) Ored[lane * 32 + tb * 16 + n * 4 + r] = o_acc[tb][n][r];
      Lred[lane][tb] = rs_acc[tb];
    }
  }
  __syncthreads();
  if (w == 0) {
#pragma unroll
    for (int tb = 0; tb < 2; ++tb) {
#pragma unroll
      for (int n = 0; n < 4; ++n)
#pragma unroll
        for (int r = 0; r < 4; ++r) o_acc[tb][n][r] += Ored[lane * 32 + tb * 16 + n * 4 + r];
      float v = rs_acc[tb] + Lred[lane][tb];
      v += __shfl_xor(v, 16, 64);
      v += __shfl_xor(v, 32, 64);
      float inv = 1.f / v;
      // normalized b64 stores: t = t0+16tb+l, c = h*64+16n+4g+r (4 consecutive)
#pragma unroll
      for (int n = 0; n < 4; ++n) {
        bf16x4 ov;
#pragma unroll
        for (int r = 0; r < 4; ++r) ov[r] = (__bf16)(o_acc[tb][n][r] * inv);
        *(bf16x4*)(outA + ((size_t)b * TI + t0 + 16 * tb + l) * 512 + h * 64 + 16 * n + 4 * g) = ov;
      }
    }
  }
}

// ---------------------------------------------------------------------------
// MFMA conv3 (k=3, SAME) + bias + transposed residual, out [B, C, T] fp32.
// (unchanged from r11 — measured good)
// ---------------------------------------------------------------------------
__global__ __launch_bounds__(256) void k_conv3_mfma(const __bf16* __restrict__ A,
                                                    const __bf16* __restrict__ W3p,
                                                    const float* __restrict__ bias,
                                                    const float* __restrict__ image,
                                                    float* __restrict__ out) {
  int b = blockIdx.z;
  int o0 = blockIdx.y * 64;
  int ob0 = o0 >> 4;
  int tid = threadIdx.x;
  int w = tid >> 6;
  int lane = tid & 63;
  int l = lane & 15;
  int g = lane >> 4;
  int t0 = blockIdx.x * 128;
  int t0w = t0 + w * 32;

  __shared__ __align__(16) __bf16 Alds[2][130 * 32];
  __shared__ __align__(16) __bf16 Wlds[2][12 * 512];

  const __bf16* Ab = A + (size_t)b * TI * 512;

  auto stage = [&](int cb, int buf) {
#pragma unroll
    for (int pass = 0; pass < 3; ++pass) {
      int gi = tid + pass * 256;
      if (gi < 520) {
        int r = gi >> 2, gg = gi & 3;
        int t = t0 - 1 + r;
        bf16x8 v = {};
        if (t >= 0 && t < TI) v = *(const bf16x8*)(Ab + (size_t)t * 512 + cb * 32 + gg * 8);
        *(bf16x8*)&Alds[buf][r * 32 + ((gg ^ (r & 3)) << 3)] = v;
      }
    }
#pragma unroll
    for (int ch = w; ch < 12; ch += 4) {
      bf16x8 v = *(const bf16x8*)(W3p + ((((size_t)cb * 3 + (ch >> 2)) * 32 + ob0 +
                                          (ch & 3)) * 64 + lane) * 8);
      *(bf16x8*)&Wlds[buf][ch * 512 + lane * 8] = v;
    }
  };

  f32x4 acc[2][4] = {};

  stage(0, 0);
  __syncthreads();
#pragma unroll 1
  for (int cs = 0; cs < 16; ++cs) {
    int cur = cs & 1;
    if (cs < 15) stage(cs + 1, cur ^ 1);
    bf16x8 af[3][2], wf[3][4];
#pragma unroll
    for (int tap = 0; tap < 3; ++tap) {
#pragma unroll
      for (int m = 0; m < 2; ++m) {
        int r = w * 32 + 16 * m + l + tap;
        af[tap][m] = *(const bf16x8*)&Alds[cur][r * 32 + ((g ^ (r & 3)) << 3)];
      }
#pragma unroll
      for (int n = 0; n < 4; ++n)
        wf[tap][n] = *(const bf16x8*)&Wlds[cur][(tap * 4 + n) * 512 + lane * 8];
    }
#pragma unroll
    for (int tap = 0; tap < 3; ++tap)
#pragma unroll
      for (int m = 0; m < 2; ++m)
#pragma unroll
        for (int n = 0; n < 4; ++n)
          acc[m][n] =
              __builtin_amdgcn_mfma_f32_16x16x32_bf16(af[tap][m], wf[tap][n], acc[m][n], 0, 0, 0);
    __syncthreads();
  }

#pragma unroll
  for (int m = 0; m < 2; ++m) {
    int tb = t0w + 16 * m + 4 * g;
#pragma unroll
    for (int n = 0; n < 4; ++n) {
      int o = o0 + 16 * n + l;
      float bo = bias[o];
      f32x4 r;
#pragma unroll
      for (int rr = 0; rr < 4; ++rr)
        r[rr] = acc[m][n][rr] + bo + image[((size_t)b * TI + tb + rr) * CH + o];
      *(f32x4*)(out + ((size_t)b * CH + o) * TI + tb) = r;
    }
  }
}

extern "C" void kernel_launch(void* const* d_in, const int* in_sizes, int n_in,
                              void* d_out, int out_size, void* d_ws, size_t ws_size,
                              hipStream_t stream) {
  const float* image = (const float*)d_in[0];
  const float* st = (const float*)d_in[1];
  const float* xn_w = (const float*)d_in[2];
  const float* xn_b = (const float*)d_in[3];
  const float* jn_w = (const float*)d_in[4];
  const float* jn_b = (const float*)d_in[5];
  const float* xqkv_w = (const float*)d_in[6];
  const float* xqkv_b = (const float*)d_in[7];
  const float* jqkv_w = (const float*)d_in[8];
  const float* jqkv_b = (const float*)d_in[9];
  const float* proj_w = (const float*)d_in[10];
  const float* proj_b = (const float*)d_in[11];
  float* out = (float*)d_out;
  float* ws = (float*)d_ws;

  double* part = (double*)ws;                           // 2048 doubles = 16KB
  float* stats_x = ws + 4096;                           // 128 f32
  float* stats_j = ws + 4096 + 128;                     // 128 f32
  __bf16* Xnp = (__bf16*)(ws + 4096 + 256);             // packed GN'd image (8.4MB)
  __bf16* abuf = Xnp;                                   // alias: row-major attn out
  __bf16* stnp = Xnp + (size_t)2 * TI * CH;             // packed GN'd st (2.1MB)
  __bf16* wqb = stnp + (size_t)2 * TS * CH;             // packed Q weights
  __bf16* wkvb = wqb + (size_t)CH * CH;                 // packed KV weights
  __bf16* wb3 = wkvb + (size_t)2 * CH * CH;             // packed conv3 weights
  __bf16* Qp = wb3 + (size_t)3 * CH * CH;               // packed Q (8.4MB)
  __bf16* Kp = Qp + (size_t)2 * TI * CH;                // packed K (2.1MB)
  __bf16* Vp = Kp + (size_t)2 * TS * CH;                // packed V (2.1MB)

  k_gn_partial<<<dim3(1024), dim3(256), 0, stream>>>(image, st, part);
  k_gn_final<<<dim3(1), dim3(128), 0, stream>>>(part, stats_x, stats_j);

  k_gn_apply2<<<dim3(2560), dim3(256), 0, stream>>>(image, st, stats_x, stats_j,
                                                    xn_w, xn_b, jn_w, jn_b, Xnp, stnp);

  k_pack_all<<<dim3(768), dim3(256), 0, stream>>>(xqkv_w, jqkv_w, proj_w, wqb, wkvb, wb3);

  // image: Q = rows 0..511 of xqkv -> packed Q (pre-scaled by 0.125*log2e)
  k_qkv_mfma<<<dim3(TI / 128, CH / 64, 2), dim3(256), 0, stream>>>(
      Xnp, wqb, xqkv_b, Qp, nullptr, TI);
  // st: K,V = rows 512..1535 of jqkv -> packed K, packed V
  k_qkv_mfma<<<dim3(TS / 128, 1024 / 64, 2), dim3(256), 0, stream>>>(
      stnp, wkvb, jqkv_b + CH, Kp, Vp, TS);

  k_attn_mfma<<<dim3(TI / 32, 8, 2), dim3(128), 0, stream>>>(Qp, Kp, Vp, abuf);

  k_conv3_mfma<<<dim3(TI / 128, CH / 64, 2), dim3(256), 0, stream>>>(
      abuf, wb3, proj_b, image, out);
}

// Round 18
// 116.125 us; speedup vs baseline: 1.7525x; 1.4245x over previous
//
#include <hip/hip_runtime.h>
#include <math.h>

static constexpr int CH = 512;
static constexpr int GROUPS = 32;
static constexpr int HC = 64;
static constexpr float EPS = 1e-5f;
static constexpr int TI = 4096;
static constexpr int TS = 1024;

typedef __bf16 bf16x8 __attribute__((ext_vector_type(8)));
typedef __bf16 bf16x4 __attribute__((ext_vector_type(4)));
typedef float f32x4 __attribute__((ext_vector_type(4)));

// ---------------------------------------------------------------------------
// GroupNorm partial sums: 1024 blocks = {image: 512, st: 512} x (b, g, chunk).
// ---------------------------------------------------------------------------
__global__ __launch_bounds__(256) void k_gn_partial(const float* __restrict__ img,
                                                    const float* __restrict__ st,
                                                    double* __restrict__ part) {
  int bi = blockIdx.x;
  int which = bi >> 9;       // 0 = image, 1 = st
  int rem = bi & 511;
  int b = rem >> 8;
  int g = (rem >> 3) & 31;
  int chunk = rem & 7;
  const float* X = which ? st : img;
  int T = which ? TS : TI;
  int rows = T >> 3;
  int tid = threadIdx.x;
  const float* base = X + ((size_t)b * T + (size_t)chunk * rows) * CH + g * 16;
  double s1 = 0.0, s2 = 0.0;
  for (int t = tid; t < rows; t += 256) {
    const float4* p = (const float4*)(base + (size_t)t * CH);
#pragma unroll
    for (int q = 0; q < 4; ++q) {
      float4 v = p[q];
      s1 += (double)v.x + (double)v.y + (double)v.z + (double)v.w;
      s2 += (double)v.x * v.x + (double)v.y * v.y + (double)v.z * v.z + (double)v.w * v.w;
    }
  }
  __shared__ double r1[256];
  __shared__ double r2[256];
  r1[tid] = s1;
  r2[tid] = s2;
  __syncthreads();
  for (int s = 128; s > 0; s >>= 1) {
    if (tid < s) { r1[tid] += r1[tid + s]; r2[tid] += r2[tid + s]; }
    __syncthreads();
  }
  if (tid == 0) {
    part[bi * 2 + 0] = r1[0];
    part[bi * 2 + 1] = r2[0];
  }
}

// ---------------------------------------------------------------------------
// GroupNorm finalize: 128 threads, one per (which, b, g). Sums 8 partials.
// ---------------------------------------------------------------------------
__global__ __launch_bounds__(128) void k_gn_final(const double* __restrict__ part,
                                                  float* __restrict__ stats_x,
                                                  float* __restrict__ stats_j) {
  int tid = threadIdx.x;
  int which = tid >> 6;
  int idx = tid & 63;  // b*32 + g
  const double* p = part + ((which << 9) + ((idx >> 5) << 8) + ((idx & 31) << 3)) * 2;
  double s1 = 0.0, s2 = 0.0;
#pragma unroll
  for (int c = 0; c < 8; ++c) {
    s1 += p[c * 2 + 0];
    s2 += p[c * 2 + 1];
  }
  int T = which ? TS : TI;
  double N = 16.0 * T;
  double mu = s1 / N;
  double var = s2 / N - mu * mu;
  float rs = (float)(1.0 / sqrt(var + (double)EPS));
  float* stats = which ? stats_j : stats_x;
  stats[idx * 2 + 0] = (float)mu;
  stats[idx * 2 + 1] = rs;
}

// ---------------------------------------------------------------------------
// GroupNorm apply + bf16 cast for BOTH inputs (merged), writing PACKED
// A-fragment layout: Xp[b][t/16][c/32][lane][8].
// ---------------------------------------------------------------------------
__global__ __launch_bounds__(256) void k_gn_apply2(const float* __restrict__ img,
                                                   const float* __restrict__ st,
                                                   const float* __restrict__ stats_x,
                                                   const float* __restrict__ stats_j,
                                                   const float* __restrict__ xn_w,
                                                   const float* __restrict__ xn_b,
                                                   const float* __restrict__ jn_w,
                                                   const float* __restrict__ jn_b,
                                                   __bf16* __restrict__ Xnp,
                                                   __bf16* __restrict__ stnp) {
  int bi = blockIdx.x;
  bool isimg = bi < 2048;
  const float* X = isimg ? img : st;
  const float* stats = isimg ? stats_x : stats_j;
  const float* nw = isimg ? xn_w : jn_w;
  const float* nb = isimg ? xn_b : jn_b;
  __bf16* Xp = isimg ? Xnp : stnp;
  int T = isimg ? TI : TS;
  size_t idx = ((size_t)(isimg ? bi : bi - 2048) * 256 + threadIdx.x) * 8;

  int b = (int)(idx / ((size_t)T * 512));
  size_t rem = idx - (size_t)b * T * 512;
  int t = (int)(rem >> 9);
  int c = (int)(rem & 511);
  int g = c >> 4;
  float mu = stats[(b * GROUPS + g) * 2 + 0];
  float rs = stats[(b * GROUPS + g) * 2 + 1];
  float4 v0 = *(const float4*)(X + idx);
  float4 v1 = *(const float4*)(X + idx + 4);
  float4 w0 = *(const float4*)(nw + c);
  float4 w1 = *(const float4*)(nw + c + 4);
  float4 q0 = *(const float4*)(nb + c);
  float4 q1 = *(const float4*)(nb + c + 4);
  float xv[8] = {v0.x, v0.y, v0.z, v0.w, v1.x, v1.y, v1.z, v1.w};
  float wv[8] = {w0.x, w0.y, w0.z, w0.w, w1.x, w1.y, w1.z, w1.w};
  float qv[8] = {q0.x, q0.y, q0.z, q0.w, q1.x, q1.y, q1.z, q1.w};
  bf16x8 r;
#pragma unroll
  for (int i = 0; i < 8; ++i) {
    float a = rs * wv[i];
    r[i] = (__bf16)fmaf(xv[i], a, qv[i] - mu * a);
  }
  size_t off = ((((size_t)b * (T >> 4) + (t >> 4)) * 16 + (c >> 5)) * 64 +
                ((c >> 3) & 3) * 16 + (t & 15)) * 8;
  *(bf16x8*)(Xp + off) = r;
}

// ---------------------------------------------------------------------------
// Merged weight pack (all three weight tensors in one launch).
// ---------------------------------------------------------------------------
__global__ __launch_bounds__(256) void k_pack_all(const float* __restrict__ xqkv_w,
                                                  const float* __restrict__ jqkv_w,
                                                  const float* __restrict__ proj_w,
                                                  __bf16* __restrict__ wqb,
                                                  __bf16* __restrict__ wkvb,
                                                  __bf16* __restrict__ wb3) {
  int bi = blockIdx.x;
  if (bi < 384) {
    const float* W = (bi < 128) ? xqkv_w : (jqkv_w + (size_t)CH * CH);
    __bf16* Wp = (bi < 128) ? wqb : wkvb;
    int idx = ((bi < 128) ? bi : bi - 128) * 256 + threadIdx.x;
    int lane = idx & 63;
    int l = lane & 15, g = lane >> 4;
    int cb = (idx >> 6) & 15;
    int ob = idx >> 10;
    const float* src = W + (size_t)(ob * 16 + l) * 512 + cb * 32 + g * 8;
    float4 v0 = *(const float4*)src;
    float4 v1 = *(const float4*)(src + 4);
    float xv[8] = {v0.x, v0.y, v0.z, v0.w, v1.x, v1.y, v1.z, v1.w};
    bf16x8 r;
#pragma unroll
    for (int i = 0; i < 8; ++i) r[i] = (__bf16)xv[i];
    *(bf16x8*)(Wp + (size_t)idx * 8) = r;
  } else {
    int idx = (bi - 384) * 256 + threadIdx.x;
    int lane = idx & 63;
    int l = lane & 15, g = lane >> 4;
    int ob = (idx >> 6) & 31;
    int q = idx >> 11;
    int tap = q % 3;
    int cb = q / 3;
    int o = ob * 16 + l;
    int c = cb * 32 + g * 8;
    bf16x8 r;
#pragma unroll
    for (int j = 0; j < 8; ++j) r[j] = (__bf16)proj_w[((size_t)o * 512 + c + j) * 3 + tap];
    *(bf16x8*)(wb3 + (size_t)idx * 8) = r;
  }
}

// ---------------------------------------------------------------------------
// MFMA 1x1-conv GEMM on packed operands; vectorized transpose epilogues.
// ---------------------------------------------------------------------------
__global__ __launch_bounds__(256) void k_qkv_mfma(const __bf16* __restrict__ Xp,
                                                  const __bf16* __restrict__ Wp,
                                                  const float* __restrict__ bias,
                                                  __bf16* __restrict__ outQK,
                                                  __bf16* __restrict__ outVp,
                                                  int T) {
  int b = blockIdx.z;
  int o0 = blockIdx.y * 64;
  int tid = threadIdx.x;
  int w = tid >> 6;
  int lane = tid & 63;
  int l = lane & 15;
  int g = lane >> 4;
  int t0 = blockIdx.x * 128 + w * 32;
  int Tb = T >> 4;
  bool vmode = (outVp != nullptr) && (o0 >= 512);

  __shared__ __align__(16) __bf16 Elds[4][2048];  // 4KB per wave

  f32x4 acc[2][4] = {};
  const __bf16* Xb = Xp + (size_t)b * T * 512;

  auto load_c = [&](int cb, bf16x8 (&af)[2], bf16x8 (&wf)[4]) {
#pragma unroll
    for (int m = 0; m < 2; ++m)
      af[m] = *(const bf16x8*)(Xb + ((((size_t)(t0 >> 4) + m) * 16 + cb) * 64 + lane) * 8);
#pragma unroll
    for (int n = 0; n < 4; ++n)
      wf[n] = *(const bf16x8*)(Wp + ((((size_t)(o0 >> 4) + n) * 16 + cb) * 64 + lane) * 8);
  };

  bf16x8 afA[2], wfA[4], afB[2], wfB[4];
#define QKV_LOOP(MMEXPR)                                                        \
  {                                                                             \
    load_c(0, afA, wfA);                                                        \
    _Pragma("unroll") for (int cb = 0; cb < 16; cb += 2) {                      \
      load_c(cb + 1, afB, wfB);                                                 \
      _Pragma("unroll") for (int m = 0; m < 2; ++m)                             \
          _Pragma("unroll") for (int n = 0; n < 4; ++n) {                       \
        bf16x8 af = afA[m], wf = wfA[n];                                        \
        acc[m][n] = MMEXPR;                                                     \
      }                                                                         \
      if (cb + 2 < 16) load_c(cb + 2, afA, wfA);                                \
      _Pragma("unroll") for (int m = 0; m < 2; ++m)                             \
          _Pragma("unroll") for (int n = 0; n < 4; ++n) {                       \
        bf16x8 af = afB[m], wf = wfB[n];                                        \
        acc[m][n] = MMEXPR;                                                     \
      }                                                                         \
    }                                                                           \
  }

  if (!vmode) {
    // swapped: D rows = o (16n+4g+r), cols = t (16m+l)
    QKV_LOOP(__builtin_amdgcn_mfma_f32_16x16x32_bf16(wf, af, acc[m][n], 0, 0, 0))
    float sc = (outVp == nullptr) ? 0.125f * 1.44269504088896f : 1.0f;
    int swz = (l & 7) << 1;
    __bf16(*Eq)[64] = reinterpret_cast<__bf16(*)[64]>(&Elds[w][0]);  // [32][64]
#pragma unroll
    for (int m = 0; m < 2; ++m)
#pragma unroll
      for (int n = 0; n < 4; ++n) {
        f32x4 bv = *(const f32x4*)(bias + o0 + 16 * n + 4 * g);
        bf16x4 pv;
#pragma unroll
        for (int r = 0; r < 4; ++r) pv[r] = (__bf16)((acc[m][n][r] + bv[r]) * sc);
        *(bf16x4*)&Eq[m * 16 + l][((4 * n + g) ^ swz) * 4] = pv;
      }
#pragma unroll
    for (int m = 0; m < 2; ++m)
#pragma unroll
      for (int cbi = 0; cbi < 2; ++cbi) {
        bf16x8 v = *(const bf16x8*)&Eq[m * 16 + l][((8 * cbi + 2 * g) ^ swz) * 4];
        *(bf16x8*)(outQK +
                   ((((size_t)b * Tb + (t0 >> 4) + m) * 16 + (o0 >> 5) + cbi) * 64 + lane) * 8) = v;
      }
  } else {
    // unswapped: D rows = s (16m+4g+r), cols = c (16n+l)
    QKV_LOOP(__builtin_amdgcn_mfma_f32_16x16x32_bf16(af, wf, acc[m][n], 0, 0, 0))
    int swzv = l & 6;
    __bf16(*Ev)[32] = reinterpret_cast<__bf16(*)[32]>(&Elds[w][0]);  // [64 c][32 s]
#pragma unroll
    for (int m = 0; m < 2; ++m)
#pragma unroll
      for (int n = 0; n < 4; ++n) {
        float bo = bias[o0 + 16 * n + l];
        bf16x4 pv;
#pragma unroll
        for (int r = 0; r < 4; ++r) pv[r] = (__bf16)(acc[m][n][r] + bo);
        *(bf16x4*)&Ev[16 * n + l][((4 * m + g) ^ swzv) * 4] = pv;
      }
#pragma unroll
    for (int n = 0; n < 4; ++n) {
      bf16x8 v = *(const bf16x8*)&Ev[16 * n + l][((2 * g) ^ swzv) * 4];
      int cb16 = ((o0 - 512) >> 4) + n;
      *(bf16x8*)(outVp + ((((size_t)b * 32 + cb16) * 32 + (t0 >> 5)) * 64 + lane) * 8) = v;
    }
  }
#undef QKV_LOOP
}

// ---------------------------------------------------------------------------
// MFMA flash cross-attention, swapped-QK form, s-split across 2 waves.
// r13 instruction stream (best measured); Ored aliased onto the P-LDS region
// (dead after the s-loop) behind a barrier. Qp pre-scaled by 0.125*log2e.
// NOTE: this body sits on a register-allocation cliff — r9/r12/r14/r16/r17
// each perturbed it (pipelining, unroll, launch-bounds, even setprio) and
// every variant spilled to scratch. Do not modify without checking FETCH.
// ---------------------------------------------------------------------------
__global__ __launch_bounds__(128, 4) void k_attn_mfma(const __bf16* __restrict__ Qp,
                                                      const __bf16* __restrict__ Kp,
                                                      const __bf16* __restrict__ Vp,
                                                      __bf16* __restrict__ outA) {
  int b = blockIdx.z;
  int h = blockIdx.y;
  int tid = threadIdx.x;
  int w = tid >> 6;  // s-half
  int lane = tid & 63;
  int l = lane & 15;
  int g = lane >> 4;
  int t0 = blockIdx.x * 32;
  int swz = (l & 7) << 1;

  __shared__ __align__(16) __bf16 Pt[2][2][16][64];  // [wave][tb][t-row l][s], 8KB
  __shared__ float Lred[64][2];
  // Ored aliases the whole Pt region (dead after both waves' s-loops).
  float* Ored = (float*)&Pt[0][0][0][0];  // 64 lanes x 32 floats = 8KB

  // Q fragments (packed, contiguous per wave)
  bf16x8 qf[2][2];
#pragma unroll
  for (int m = 0; m < 2; ++m)
#pragma unroll
    for (int ks = 0; ks < 2; ++ks)
      qf[m][ks] = *(const bf16x8*)(Qp + ((((size_t)b * 256 + (t0 >> 4) + m) * 16 +
                                          2 * h + ks) * 64 + lane) * 8);

  f32x4 o_acc[2][4] = {};  // [tb][n]: c = 16n+4g+r, t = 16tb+l
  float rs_acc[2] = {};

  int s_base = w * 512;
#pragma unroll 1
  for (int s0 = s_base; s0 < s_base + 512; s0 += 64) {
    // K fragments (packed)
    bf16x8 kf[4][2];
#pragma unroll
    for (int n = 0; n < 4; ++n)
#pragma unroll
      for (int ks = 0; ks < 2; ++ks)
        kf[n][ks] = *(const bf16x8*)(Kp + ((((size_t)b * 64 + (s0 >> 4) + n) * 16 +
                                            2 * h + ks) * 64 + lane) * 8);
    // V fragments (packed)
    bf16x8 vf[4][2];
#pragma unroll
    for (int n = 0; n < 4; ++n)
#pragma unroll
      for (int ks = 0; ks < 2; ++ks)
        vf[n][ks] = *(const bf16x8*)(Vp + ((((size_t)b * 32 + h * 4 + n) * 32 +
                                            (s0 >> 5) + ks) * 64 + lane) * 8);
    // S^T = K Q^T : sT[sb][tb], row s = 16sb+4g+r, col t = 16tb+l
    f32x4 sT[4][2];
#pragma unroll
    for (int sb = 0; sb < 4; ++sb)
#pragma unroll
      for (int tb = 0; tb < 2; ++tb) {
        f32x4 z = {0.f, 0.f, 0.f, 0.f};
        z = __builtin_amdgcn_mfma_f32_16x16x32_bf16(kf[sb][0], qf[tb][0], z, 0, 0, 0);
        sT[sb][tb] = __builtin_amdgcn_mfma_f32_16x16x32_bf16(kf[sb][1], qf[tb][1], z, 0, 0, 0);
      }
    // p = exp2(S*log2e); partial t-row sums; vectorized b64 P writes
#pragma unroll
    for (int tb = 0; tb < 2; ++tb)
#pragma unroll
      for (int sb = 0; sb < 4; ++sb) {
        float p0 = exp2f(sT[sb][tb][0]);
        float p1 = exp2f(sT[sb][tb][1]);
        float p2 = exp2f(sT[sb][tb][2]);
        float p3 = exp2f(sT[sb][tb][3]);
        rs_acc[tb] += (p0 + p1) + (p2 + p3);
        bf16x4 pv;
        pv[0] = (__bf16)p0;
        pv[1] = (__bf16)p1;
        pv[2] = (__bf16)p2;
        pv[3] = (__bf16)p3;
        *(bf16x4*)&Pt[w][tb][l][((4 * sb + g) ^ swz) * 4] = pv;
      }
    // P B-fragments: col t = 16tb+l, k = s = 32ks+8g+i
    bf16x8 pa[2][2];
#pragma unroll
    for (int tb = 0; tb < 2; ++tb)
#pragma unroll
      for (int ks = 0; ks < 2; ++ks)
        pa[tb][ks] = *(const bf16x8*)&Pt[w][tb][l][((8 * ks + 2 * g) ^ swz) * 4];
    // O^T += V P : D rows c = 16n+4g+r, cols t = 16tb+l
#pragma unroll
    for (int tb = 0; tb < 2; ++tb)
#pragma unroll
      for (int n = 0; n < 4; ++n) {
        o_acc[tb][n] = __builtin_amdgcn_mfma_f32_16x16x32_bf16(vf[n][0], pa[tb][0], o_acc[tb][n], 0, 0, 0);
        o_acc[tb][n] = __builtin_amdgcn_mfma_f32_16x16x32_bf16(vf[n][1], pa[tb][1], o_acc[tb][n], 0, 0, 0);
      }
  }

  // cross-wave combine (linear in s). Pt is dead for BOTH waves after this
  // barrier, so wave 1's partial O can safely overwrite it.
  __syncthreads();
  if (w == 1) {
#pragma unroll
    for (int tb = 0; tb < 2; ++tb) {
#pragma unroll
      for (int n = 0; n < 4; ++n)
#pragma unroll
        for (int r = 0; r < 4; ++r) Ored[lane * 32 + tb * 16 + n * 4 + r] = o_acc[tb][n][r];
      Lred[lane][tb] = rs_acc[tb];
    }
  }
  __syncthreads();
  if (w == 0) {
#pragma unroll
    for (int tb = 0; tb < 2; ++tb) {
#pragma unroll
      for (int n = 0; n < 4; ++n)
#pragma unroll
        for (int r = 0; r < 4; ++r) o_acc[tb][n][r] += Ored[lane * 32 + tb * 16 + n * 4 + r];
      float v = rs_acc[tb] + Lred[lane][tb];
      v += __shfl_xor(v, 16, 64);
      v += __shfl_xor(v, 32, 64);
      float inv = 1.f / v;
      // normalized b64 stores: t = t0+16tb+l, c = h*64+16n+4g+r (4 consecutive)
#pragma unroll
      for (int n = 0; n < 4; ++n) {
        bf16x4 ov;
#pragma unroll
        for (int r = 0; r < 4; ++r) ov[r] = (__bf16)(o_acc[tb][n][r] * inv);
        *(bf16x4*)(outA + ((size_t)b * TI + t0 + 16 * tb + l) * 512 + h * 64 + 16 * n + 4 * g) = ov;
      }
    }
  }
}

// ---------------------------------------------------------------------------
// MFMA conv3 (k=3, SAME) + bias + transposed residual, out [B, C, T] fp32.
// ---------------------------------------------------------------------------
__global__ __launch_bounds__(256) void k_conv3_mfma(const __bf16* __restrict__ A,
                                                    const __bf16* __restrict__ W3p,
                                                    const float* __restrict__ bias,
                                                    const float* __restrict__ image,
                                                    float* __restrict__ out) {
  int b = blockIdx.z;
  int o0 = blockIdx.y * 64;
  int ob0 = o0 >> 4;
  int tid = threadIdx.x;
  int w = tid >> 6;
  int lane = tid & 63;
  int l = lane & 15;
  int g = lane >> 4;
  int t0 = blockIdx.x * 128;
  int t0w = t0 + w * 32;

  __shared__ __align__(16) __bf16 Alds[2][130 * 32];
  __shared__ __align__(16) __bf16 Wlds[2][12 * 512];

  const __bf16* Ab = A + (size_t)b * TI * 512;

  auto stage = [&](int cb, int buf) {
#pragma unroll
    for (int pass = 0; pass < 3; ++pass) {
      int gi = tid + pass * 256;
      if (gi < 520) {
        int r = gi >> 2, gg = gi & 3;
        int t = t0 - 1 + r;
        bf16x8 v = {};
        if (t >= 0 && t < TI) v = *(const bf16x8*)(Ab + (size_t)t * 512 + cb * 32 + gg * 8);
        *(bf16x8*)&Alds[buf][r * 32 + ((gg ^ (r & 3)) << 3)] = v;
      }
    }
#pragma unroll
    for (int ch = w; ch < 12; ch += 4) {
      bf16x8 v = *(const bf16x8*)(W3p + ((((size_t)cb * 3 + (ch >> 2)) * 32 + ob0 +
                                          (ch & 3)) * 64 + lane) * 8);
      *(bf16x8*)&Wlds[buf][ch * 512 + lane * 8] = v;
    }
  };

  f32x4 acc[2][4] = {};

  stage(0, 0);
  __syncthreads();
#pragma unroll 1
  for (int cs = 0; cs < 16; ++cs) {
    int cur = cs & 1;
    if (cs < 15) stage(cs + 1, cur ^ 1);
    bf16x8 af[3][2], wf[3][4];
#pragma unroll
    for (int tap = 0; tap < 3; ++tap) {
#pragma unroll
      for (int m = 0; m < 2; ++m) {
        int r = w * 32 + 16 * m + l + tap;
        af[tap][m] = *(const bf16x8*)&Alds[cur][r * 32 + ((g ^ (r & 3)) << 3)];
      }
#pragma unroll
      for (int n = 0; n < 4; ++n)
        wf[tap][n] = *(const bf16x8*)&Wlds[cur][(tap * 4 + n) * 512 + lane * 8];
    }
#pragma unroll
    for (int tap = 0; tap < 3; ++tap)
#pragma unroll
      for (int m = 0; m < 2; ++m)
#pragma unroll
        for (int n = 0; n < 4; ++n)
          acc[m][n] =
              __builtin_amdgcn_mfma_f32_16x16x32_bf16(af[tap][m], wf[tap][n], acc[m][n], 0, 0, 0);
    __syncthreads();
  }

#pragma unroll
  for (int m = 0; m < 2; ++m) {
    int tb = t0w + 16 * m + 4 * g;
#pragma unroll
    for (int n = 0; n < 4; ++n) {
      int o = o0 + 16 * n + l;
      float bo = bias[o];
      f32x4 r;
#pragma unroll
      for (int rr = 0; rr < 4; ++rr)
        r[rr] = acc[m][n][rr] + bo + image[((size_t)b * TI + tb + rr) * CH + o];
      *(f32x4*)(out + ((size_t)b * CH + o) * TI + tb) = r;
    }
  }
}

extern "C" void kernel_launch(void* const* d_in, const int* in_sizes, int n_in,
                              void* d_out, int out_size, void* d_ws, size_t ws_size,
                              hipStream_t stream) {
  const float* image = (const float*)d_in[0];
  const float* st = (const float*)d_in[1];
  const float* xn_w = (const float*)d_in[2];
  const float* xn_b = (const float*)d_in[3];
  const float* jn_w = (const float*)d_in[4];
  const float* jn_b = (const float*)d_in[5];
  const float* xqkv_w = (const float*)d_in[6];
  const float* xqkv_b = (const float*)d_in[7];
  const float* jqkv_w = (const float*)d_in[8];
  const float* jqkv_b = (const float*)d_in[9];
  const float* proj_w = (const float*)d_in[10];
  const float* proj_b = (const float*)d_in[11];
  float* out = (float*)d_out;
  float* ws = (float*)d_ws;

  double* part = (double*)ws;                           // 2048 doubles = 16KB
  float* stats_x = ws + 4096;                           // 128 f32
  float* stats_j = ws + 4096 + 128;                     // 128 f32
  __bf16* Xnp = (__bf16*)(ws + 4096 + 256);             // packed GN'd image (8.4MB)
  __bf16* abuf = Xnp;                                   // alias: row-major attn out
  __bf16* stnp = Xnp + (size_t)2 * TI * CH;             // packed GN'd st (2.1MB)
  __bf16* wqb = stnp + (size_t)2 * TS * CH;             // packed Q weights
  __bf16* wkvb = wqb + (size_t)CH * CH;                 // packed KV weights
  __bf16* wb3 = wkvb + (size_t)2 * CH * CH;             // packed conv3 weights
  __bf16* Qp = wb3 + (size_t)3 * CH * CH;               // packed Q (8.4MB)
  __bf16* Kp = Qp + (size_t)2 * TI * CH;                // packed K (2.1MB)
  __bf16* Vp = Kp + (size_t)2 * TS * CH;                // packed V (2.1MB)

  k_gn_partial<<<dim3(1024), dim3(256), 0, stream>>>(image, st, part);
  k_gn_final<<<dim3(1), dim3(128), 0, stream>>>(part, stats_x, stats_j);

  k_gn_apply2<<<dim3(2560), dim3(256), 0, stream>>>(image, st, stats_x, stats_j,
                                                    xn_w, xn_b, jn_w, jn_b, Xnp, stnp);

  k_pack_all<<<dim3(768), dim3(256), 0, stream>>>(xqkv_w, jqkv_w, proj_w, wqb, wkvb, wb3);

  // image: Q = rows 0..511 of xqkv -> packed Q (pre-scaled by 0.125*log2e)
  k_qkv_mfma<<<dim3(TI / 128, CH / 64, 2), dim3(256), 0, stream>>>(
      Xnp, wqb, xqkv_b, Qp, nullptr, TI);
  // st: K,V = rows 512..1535 of jqkv -> packed K, packed V
  k_qkv_mfma<<<dim3(TS / 128, 1024 / 64, 2), dim3(256), 0, stream>>>(
      stnp, wkvb, jqkv_b + CH, Kp, Vp, TS);

  k_attn_mfma<<<dim3(TI / 32, 8, 2), dim3(128), 0, stream>>>(Qp, Kp, Vp, abuf);

  k_conv3_mfma<<<dim3(TI / 128, CH / 64, 2), dim3(256), 0, stream>>>(
      abuf, wb3, proj_b, image, out);
}